// Round 11
// baseline (234.859 us; speedup 1.0000x reference)
//
#include <hip/hip_runtime.h>
#include <math.h>

#define B_ 2
#define T_ 2048
#define C_ 1024
#define H_ 16
#define HD_ 64
#define M_ (B_*T_)

typedef _Float16 half2v __attribute__((ext_vector_type(2)));
typedef _Float16 half4v __attribute__((ext_vector_type(4)));
typedef _Float16 half8v __attribute__((ext_vector_type(8)));
typedef float f32x4 __attribute__((ext_vector_type(4)));

#define GLD_LDS(gp, lp) \
  __builtin_amdgcn_global_load_lds( \
      (const __attribute__((address_space(1))) void*)(gp), \
      (__attribute__((address_space(3))) void*)(lp), 16, 0, 0)

// ---------------------------------------------------------------------------
// Fused prep: fp32->f16 cast of x (blocks 0..4095), 4 weight transposes
// (blocks 4096..8191), bias concat (blocks 8192..8203). One launch.
// ---------------------------------------------------------------------------
__global__ __launch_bounds__(256) void prep_kernel(
    const float* __restrict__ x,
    const float* __restrict__ Wq, const float* __restrict__ Wk,
    const float* __restrict__ Wv, const float* __restrict__ Wo,
    const float* __restrict__ bq, const float* __restrict__ bk,
    const float* __restrict__ bv,
    _Float16* __restrict__ xh, _Float16* __restrict__ Wt3,
    _Float16* __restrict__ Wot, float* __restrict__ b3)
{
  __shared__ float tile[32][33];
  const int blk = blockIdx.x, thr = threadIdx.x;
  if (blk < 4096) {
    int i = blk * 256 + thr;
    float4 v = ((const float4*)x)[i];
    half4v h; h[0] = (_Float16)v.x; h[1] = (_Float16)v.y;
    h[2] = (_Float16)v.z; h[3] = (_Float16)v.w;
    ((half4v*)xh)[i] = h;
  } else if (blk < 8192) {
    int zz = (blk - 4096) >> 10;      // which W
    int bxy = (blk - 4096) & 1023;
    const float* W; _Float16* Wt;
    switch (zz) {
      case 0:  W = Wq; Wt = Wt3; break;
      case 1:  W = Wk; Wt = Wt3 + (size_t)1024 * 1024; break;
      case 2:  W = Wv; Wt = Wt3 + (size_t)2048 * 1024; break;
      default: W = Wo; Wt = Wot; break;
    }
    const int n0 = (bxy & 31) * 32, k0 = (bxy >> 5) * 32;
    const int tx = thr & 31, ty = thr >> 5;  // 32 x 8
#pragma unroll
    for (int r = 0; r < 4; r++) {
      int k = ty + r * 8;
      tile[k][tx] = W[(size_t)(k0 + k) * C_ + n0 + tx];
    }
    __syncthreads();
#pragma unroll
    for (int r = 0; r < 4; r++) {
      int n = ty + r * 8;
      Wt[(size_t)(n0 + n) * C_ + k0 + tx] = (_Float16)tile[tx][n];
    }
  } else {
    int i = (blk - 8192) * 256 + thr;  // 0..3071
    const float* s = (i < 1024) ? bq : ((i < 2048) ? bk : bv);
    b3[i] = s[i & 1023];
  }
}

// ---------------------------------------------------------------------------
// f16 MFMA GEMM: Out[M,N] = A[M,1024] @ Wt[N,1024]^T + bias.
// BK=32, 256 threads = 4 waves (2x2); wave tile (BM/2)x(BN/2).
// Staging via global_load_lds width=16 (m97 pattern).
// EPI 0: fused QKV epilogue. Q (scaled 0.125*log2e) and K: plain 2-B stores.
//   V: r=0..3 are 4 consecutive t in Vt[b,h,d,t] -> one packed 8-B store.
// EPI 1: fp32 out + bias (of).
// ---------------------------------------------------------------------------
template <int BM, int BN, int EPI>
__global__ __launch_bounds__(256) void gemm_f16_kernel(
    const _Float16* __restrict__ A, const _Float16* __restrict__ Bw,
    const float* __restrict__ bias,
    _Float16* __restrict__ o0, _Float16* __restrict__ o1,
    _Float16* __restrict__ o2, float* __restrict__ of)
{
  constexpr int FM = BM / 32, FN = BN / 32;
  __shared__ __align__(16) _Float16 As[BM * 32];
  __shared__ __align__(16) _Float16 Bs[BN * 32];
  const int t = threadIdx.x;
  const int w = t >> 6, lane = t & 63, l15 = lane & 15, quad = lane >> 4;
  const int wm = (w & 1) * (BM / 2), wn = (w >> 1) * (BN / 2);
  const int bm = blockIdx.y * BM, bn = blockIdx.x * BN;
  const int lrow = lane >> 2, lcol = (lane & 3) * 8;  // staging: 16 rows/call

  f32x4 acc[FM][FN];
#pragma unroll
  for (int i = 0; i < FM; i++)
#pragma unroll
    for (int j = 0; j < FN; j++) acc[i][j] = (f32x4){0.f, 0.f, 0.f, 0.f};

  for (int k0 = 0; k0 < 1024; k0 += 32) {
#pragma unroll
    for (int i = 0; i < BM / 64; i++) {
      int ca = w + 4 * i;
      int row = ca * 16 + lrow;
      GLD_LDS(A + (size_t)(bm + row) * 1024 + k0 + lcol, As + ca * 512);
    }
#pragma unroll
    for (int i = 0; i < BN / 64; i++) {
      int cb = w + 4 * i;
      int row = cb * 16 + lrow;
      GLD_LDS(Bw + (size_t)(bn + row) * 1024 + k0 + lcol, Bs + cb * 512);
    }
    __syncthreads();

    half8v af[FM], bf[FN];
#pragma unroll
    for (int mt = 0; mt < FM; mt++)
      af[mt] = *(const half8v*)(As + (wm + mt * 16 + l15) * 32 + quad * 8);
#pragma unroll
    for (int nt = 0; nt < FN; nt++)
      bf[nt] = *(const half8v*)(Bs + (wn + nt * 16 + l15) * 32 + quad * 8);
#pragma unroll
    for (int mt = 0; mt < FM; mt++)
#pragma unroll
      for (int nt = 0; nt < FN; nt++)
        acc[mt][nt] = __builtin_amdgcn_mfma_f32_16x16x32_f16(
            af[mt], bf[nt], acc[mt][nt], 0, 0, 0);
    __syncthreads();
  }

  // Epilogue. C/D layout: col = l15 (n), row = quad*4 + r (m).
#pragma unroll
  for (int mt = 0; mt < FM; mt++)
#pragma unroll
    for (int nt = 0; nt < FN; nt++) {
      int n = bn + wn + nt * 16 + l15;
      float bv = bias[n];
      if (EPI == 0 && bn >= 2048) {
        // V region: pack r=0..3 (consecutive t) -> one 8-B store to V^T.
        int dg = n - 2048;
        int hh = dg >> 6, hd = dg & 63;
        int m0 = bm + wm + mt * 16 + quad * 4;
        int bb = m0 >> 11, tt = m0 & 2047;
        half2v p01 = __builtin_bit_cast(half2v,
            __builtin_amdgcn_cvt_pkrtz(acc[mt][nt][0] + bv, acc[mt][nt][1] + bv));
        half2v p23 = __builtin_bit_cast(half2v,
            __builtin_amdgcn_cvt_pkrtz(acc[mt][nt][2] + bv, acc[mt][nt][3] + bv));
        half4v pk = __builtin_shufflevector(p01, p23, 0, 1, 2, 3);
        *(half4v*)(o2 + (((size_t)(bb * H_ + hh) * 64 + hd) * 2048 + tt)) = pk;
      } else {
#pragma unroll
        for (int r = 0; r < 4; r++) {
          int m = bm + wm + mt * 16 + quad * 4 + r;
          float v = acc[mt][nt][r] + bv;
          if (EPI == 0) {
            if (bn < 1024) {
              // Q pre-scaled by 0.125 * log2(e) for base-2 softmax.
              o0[(size_t)m * 1024 + n] = (_Float16)(v * 0.180336884f);
            } else {
              o1[(size_t)m * 1024 + (n - 1024)] = (_Float16)v;    // K
            }
          } else {
            of[(size_t)m * 1024 + n] = v;
          }
        }
      }
    }
}

// ---------------------------------------------------------------------------
// MFMA flash attention, ksplit=2 across BLOCKS (flash-decode style).
// Grid (32 qt, 16 h, 4 = b*2+half), 256 thr. Each block runs r5's verbatim
// single-buffered 64-key-tile loop (static LDS bases, 2 barriers/tile) over
// ITS half of the keys (16 tiles). LDS 17.4 KB -> 8 blocks/CU -> 32 waves/CU
// (vs r10's grid-capped 16): doubles latency hiding without touching the
// proven inner loop (r7/r9 restructures lost 2.4x).
// Epilogue: normalized partial y_hat (f16) + (m,l) (f32) per q.
// ---------------------------------------------------------------------------
__global__ __launch_bounds__(256) void attn_f16_kernel(
    const _Float16* __restrict__ Qh, const _Float16* __restrict__ Kh,
    const _Float16* __restrict__ Vt, _Float16* __restrict__ part0,
    _Float16* __restrict__ part1, float* __restrict__ ml)
{
  __shared__ __align__(16) _Float16 Ks[64 * 68];
  __shared__ __align__(16) _Float16 Vs[64 * 68];
  const int t = threadIdx.x;
  const int w = t >> 6, lane = t & 63, l15 = lane & 15, quad = lane >> 4;
  const int qt = blockIdx.x, h = blockIdx.y;
  const int b = blockIdx.z >> 1, half = blockIdx.z & 1;
  const int qg = qt * 64 + w * 16 + l15;
  const size_t qoff = ((size_t)(b * T_ + qg)) * C_ + h * HD_;

  half8v qf[2];
  qf[0] = *(const half8v*)(Qh + qoff + quad * 8);
  qf[1] = *(const half8v*)(Qh + qoff + 32 + quad * 8);

  f32x4 o[4];
#pragma unroll
  for (int i = 0; i < 4; i++) o[i] = (f32x4){0.f, 0.f, 0.f, 0.f};
  float m_run = -INFINITY, l_run = 0.f;

  const size_t kbase = ((size_t)b * T_) * C_ + h * HD_;
  const size_t vbase = ((size_t)(b * H_ + h)) * HD_ * 2048;

  const int srow = t >> 3, scp = t & 7;  // staging: 8x16B chunks per row
  const int k0g = half * 1024;

  for (int kt0 = 0; kt0 < 1024; kt0 += 64) {
    const int kg = k0g + kt0;
    // Stage K (64 keys x 64 d) and V^T (64 d x 64 keys), rows padded 136 B.
#pragma unroll
    for (int i = 0; i < 2; i++) {
      int row = srow + i * 32;
      *(uint4*)((char*)Ks + row * 136 + scp * 16) =
          *(const uint4*)(Kh + kbase + (size_t)(kg + row) * C_ + scp * 8);
      *(uint4*)((char*)Vs + row * 136 + scp * 16) =
          *(const uint4*)(Vt + vbase + (size_t)row * 2048 + kg + scp * 8);
    }
    __syncthreads();

    // S^T tiles: 4 key-tiles x 2 d-steps of 16x16x32.
    f32x4 s[4];
#pragma unroll
    for (int kt = 0; kt < 4; kt++) {
      s[kt] = (f32x4){0.f, 0.f, 0.f, 0.f};
      int key = kt * 16 + l15;
#pragma unroll
      for (int ks = 0; ks < 2; ks++) {
        half8v kf = *(const half8v*)((char*)Ks + key * 136 + (ks * 4 + quad) * 16);
        s[kt] = __builtin_amdgcn_mfma_f32_16x16x32_f16(kf, qf[ks], s[kt], 0, 0, 0);
      }
    }

    // Online softmax (base-2), per q column = l15.
    float tmax = -INFINITY;
#pragma unroll
    for (int kt = 0; kt < 4; kt++)
#pragma unroll
      for (int r = 0; r < 4; r++) tmax = fmaxf(tmax, s[kt][r]);
    tmax = fmaxf(tmax, __shfl_xor(tmax, 16));
    tmax = fmaxf(tmax, __shfl_xor(tmax, 32));
    float mnew = fmaxf(m_run, tmax);
    float alpha = __builtin_amdgcn_exp2f(m_run - mnew);

    float psum = 0.f;
    half4v pf[4];
#pragma unroll
    for (int kt = 0; kt < 4; kt++) {
      float p0 = __builtin_amdgcn_exp2f(s[kt][0] - mnew);
      float p1 = __builtin_amdgcn_exp2f(s[kt][1] - mnew);
      float p2 = __builtin_amdgcn_exp2f(s[kt][2] - mnew);
      float p3 = __builtin_amdgcn_exp2f(s[kt][3] - mnew);
      psum += (p0 + p1) + (p2 + p3);
      half2v pk01 = __builtin_bit_cast(half2v, __builtin_amdgcn_cvt_pkrtz(p0, p1));
      half2v pk23 = __builtin_bit_cast(half2v, __builtin_amdgcn_cvt_pkrtz(p2, p3));
      pf[kt] = __builtin_shufflevector(pk01, pk23, 0, 1, 2, 3);
    }
    psum += __shfl_xor(psum, 16);
    psum += __shfl_xor(psum, 32);
    l_run = l_run * alpha + psum;
    m_run = mnew;
#pragma unroll
    for (int dt = 0; dt < 4; dt++) o[dt] *= alpha;

    // PV: o^T[d][q] += V^T x P, 4 d-tiles x 4 key-tiles of 16x16x16.
#pragma unroll
    for (int dt = 0; dt < 4; dt++) {
      int d = dt * 16 + l15;
#pragma unroll
      for (int kt = 0; kt < 4; kt++) {
        half4v vf = *(const half4v*)((char*)Vs + d * 136 + kt * 32 + quad * 8);
        o[dt] = __builtin_amdgcn_mfma_f32_16x16x16f16(vf, pf[kt], o[dt], 0, 0, 0);
      }
    }
    __syncthreads();
  }

  // Partial epilogue: normalized y_hat -> part[half], (m,l) -> ml.
  float inv = 1.0f / l_run;
  _Float16* pp = half ? part1 : part0;
  const int q = w * 16 + l15;
  const size_t pbase = ((((size_t)(b * H_ + h)) * 32 + qt) * 64 + q) * 64;
#pragma unroll
  for (int dt = 0; dt < 4; dt++) {
    half4v yv;
#pragma unroll
    for (int r = 0; r < 4; r++) yv[r] = (_Float16)(o[dt][r] * inv);
    *(half4v*)(pp + pbase + dt * 16 + quad * 4) = yv;
  }
  if (quad == 0) {
    size_t mlb = (size_t)half * 131072 +
                 ((((size_t)(b * H_ + h)) * 32 + qt) * 64 + q) * 2;
    ml[mlb] = m_run; ml[mlb + 1] = l_run;
  }
}

// ---------------------------------------------------------------------------
// Merge the two key-halves: y = w0*y_hat0 + w1*y_hat1,
// w_i = exp2(m_i - m) * l_i / sum. Grid (32,16,2), 256 thr; thread handles
// (q = t>>2, 16 d at (t&3)*16); fully coalesced 32-B reads/writes.
// ---------------------------------------------------------------------------
__global__ __launch_bounds__(256) void attn_merge_kernel(
    const _Float16* __restrict__ part0, const _Float16* __restrict__ part1,
    const float* __restrict__ ml, _Float16* __restrict__ Yh)
{
  const int qt = blockIdx.x, h = blockIdx.y, b = blockIdx.z;
  const int t = threadIdx.x;
  const int q = t >> 2, dc = (t & 3) * 16;
  const size_t rowi = (((size_t)(b * H_ + h)) * 32 + qt) * 64 + q;
  const size_t pbase = rowi * 64 + dc;
  float m0 = ml[rowi * 2], l0 = ml[rowi * 2 + 1];
  float m1 = ml[131072 + rowi * 2], l1 = ml[131072 + rowi * 2 + 1];
  float m = fmaxf(m0, m1);
  float a0 = __builtin_amdgcn_exp2f(m0 - m) * l0;
  float a1 = __builtin_amdgcn_exp2f(m1 - m) * l1;
  float inv = 1.0f / (a0 + a1);
  float w0 = a0 * inv, w1 = a1 * inv;
  half8v x0a = *(const half8v*)(part0 + pbase);
  half8v x0b = *(const half8v*)(part0 + pbase + 8);
  half8v x1a = *(const half8v*)(part1 + pbase);
  half8v x1b = *(const half8v*)(part1 + pbase + 8);
  half8v ya, yb;
#pragma unroll
  for (int j = 0; j < 8; j++) {
    ya[j] = (_Float16)(w0 * (float)x0a[j] + w1 * (float)x1a[j]);
    yb[j] = (_Float16)(w0 * (float)x0b[j] + w1 * (float)x1b[j]);
  }
  _Float16* yp = Yh + ((size_t)(b * T_ + qt * 64 + q)) * C_ + h * HD_ + dc;
  *(half8v*)yp = ya;
  *(half8v*)(yp + 8) = yb;
}

// ---------------------------------------------------------------------------
extern "C" void kernel_launch(void* const* d_in, const int* in_sizes, int n_in,
                              void* d_out, int out_size, void* d_ws, size_t ws_size,
                              hipStream_t stream) {
  const float* x  = (const float*)d_in[0];
  const float* Wq = (const float*)d_in[1];
  const float* bq = (const float*)d_in[2];
  const float* Wk = (const float*)d_in[3];
  const float* bk = (const float*)d_in[4];
  const float* Wv = (const float*)d_in[5];
  const float* bv = (const float*)d_in[6];
  const float* Wo = (const float*)d_in[7];
  const float* bo = (const float*)d_in[8];
  float* out = (float*)d_out;

  // Workspace carve-up (bytes). Regions are REUSED across phases:
  //  - part1 overlays xh   (xh dead after QKV GEMM)
  //  - part0 overlays slot5 (never live before attn)
  //  - merged Y overlays Kh (Kh dead after attn); feeds output GEMM.
  char* ws = (char*)d_ws;
  _Float16* xh    = (_Float16*)(ws);                        // 8 MB
  _Float16* Qh    = (_Float16*)(ws + (((size_t)8)  << 20)); // 8 MB
  _Float16* Kh    = (_Float16*)(ws + (((size_t)16) << 20)); // 8 MB
  _Float16* Vt    = (_Float16*)(ws + (((size_t)24) << 20)); // 8 MB  [b,h,d,t]
  _Float16* part0 = (_Float16*)(ws + (((size_t)32) << 20)); // 8 MB
  _Float16* part1 = xh;                                     // overlay
  _Float16* Ym    = Kh;                                     // overlay
  _Float16* Wt3   = (_Float16*)(ws + (((size_t)40) << 20)); // 6 MB  [3072][1024]
  _Float16* Wot   = (_Float16*)(ws + (((size_t)46) << 20)); // 2 MB  [1024][1024]
  float*    b3    = (float*)   (ws + (((size_t)48) << 20)); // 12 KB
  float*    ml    = (float*)   (ws + (((size_t)48) << 20) + 65536); // 1.05 MB

  prep_kernel<<<8204, 256, 0, stream>>>(x, Wq, Wk, Wv, Wo, bq, bk, bv,
                                        xh, Wt3, Wot, b3);

  // Fused QKV projection: [4096,1024] @ [1024,3072] -> Q,K (f16) + V^T (f16).
  gemm_f16_kernel<128, 128, 0><<<dim3(24, 32), 256, 0, stream>>>(
      xh, Wt3, b3, Qh, Kh, Vt, nullptr);

  attn_f16_kernel<<<dim3(32, 16, 4), 256, 0, stream>>>(
      Qh, Kh, Vt, part0, part1, ml);
  attn_merge_kernel<<<dim3(32, 16, 2), 256, 0, stream>>>(part0, part1, ml, Ym);

  // Output projection: Ym @ Wot^T + bo -> fp32 out.
  gemm_f16_kernel<64, 128, 1><<<dim3(8, 64), 256, 0, stream>>>(
      Ym, Wot, bo, nullptr, nullptr, nullptr, out);
}